// Round 1
// baseline (42413.950 us; speedup 1.0000x reference)
//
#include <hip/hip_runtime.h>
#include <hip/hip_bf16.h>

// Bidirectional GRU encoder, B=64 T=1024 D=300 U=300.
// Round 5: replace the 15-WG-per-direction cooperative scan (agent-scope
// fences + atomic barrier = 13.2 us/step, whole-L2 invalidated every step)
// with ONE 512-thread workgroup per direction. h state lives in LDS
// (bf16 hi/lo, in-place, exclusive (row,col) ownership), sync is two
// __syncthreads per step, recurrent weights stream from the XCD-local L2
// (never invalidated now) double-buffered behind the MFMAs.
// Wave layout (balanced per SIMD pair): waves 0-3 own 48 u-cols (9 n-tiles),
// waves 4-7 own 32 u-cols (6 n-tiles; wave 7: 12 real). Gate-interleaved
// B packing [z16|r16|h16] per 16-col block puts z/r/h for one output in the
// SAME lane -> fully in-register epilogue (no rp staging through LDS).

#define B_   64
#define T_   1024
#define D_   300
#define U_   300
#define NU   900      // 3U
#define KP   320      // padded K for input GEMM
#define NP   960      // padded N width of k_pad
#define XPW  912      // xp row stride (elements)
#define KB_  10       // K blocks of 32 (320/32)
#define FRAGS_PER_DIR 600   // 4 waves*90 + 4 waves*60

typedef short short8 __attribute__((ext_vector_type(8)));
typedef float floatx4 __attribute__((ext_vector_type(4)));

__device__ __forceinline__ float b2f_bits(unsigned short u) {
  union { unsigned int i; float f; } v; v.i = ((unsigned int)u) << 16; return v.f;
}
__device__ __forceinline__ unsigned short f2b(float f) {
  __hip_bfloat16 h = __float2bfloat16(f);  // RNE
  return *reinterpret_cast<unsigned short*>(&h);
}

// ---------------- K_detect: input dtype + mask dtype flags ----------------
__global__ __launch_bounds__(64) void k_detect(const unsigned int* __restrict__ xw,
                                               const unsigned char* __restrict__ mb,
                                               int* __restrict__ flags) {
  __shared__ int red[64];
  int tid = threadIdx.x;
  int hits = 0;
  for (int i = tid; i < 2048; i += 64) {
    unsigned int lo = xw[i] & 0xFFFFu;
    int e = (int)((lo >> 7) & 0xFF);
    if (e >= 105 && e <= 135) hits++;   // plausible bf16 exponent for N(0,1)
  }
  red[tid] = hits;
  __syncthreads();
  if (tid == 0) {
    int s = 0;
    for (int i = 0; i < 64; ++i) s += red[i];
    flags[0] = (s >= 1024) ? 1 : 0;
    unsigned char b0 = mb[0], b1 = mb[1];
    flags[1] = (b1 == 0) ? 0 : ((b0 == 1 && b1 == 1) ? 1 : 2);
  }
}

// ---------------- K0: lengths from mask ----------------
__global__ __launch_bounds__(256) void k_lengths(const unsigned char* __restrict__ mraw,
                                                 const int* __restrict__ flags,
                                                 int* __restrict__ lens) {
  __shared__ int red[256];
  int b = blockIdx.x, tid = threadIdx.x;
  int mt = flags[1];
  int s = 0;
  if (mt == 0) {
    const int* m = (const int*)mraw;
    for (int t = tid; t < T_; t += 256) s += m[(size_t)b * T_ + t] ? 1 : 0;
  } else if (mt == 1) {
    for (int t = tid; t < T_; t += 256) s += mraw[(size_t)b * T_ + t] ? 1 : 0;
  } else {
    const unsigned short* m = (const unsigned short*)mraw;
    for (int t = tid; t < T_; t += 256) s += m[(size_t)b * T_ + t] ? 1 : 0;
  }
  red[tid] = s; __syncthreads();
  for (int off = 128; off > 0; off >>= 1) {
    if (tid < off) red[tid] += red[tid + off];
    __syncthreads();
  }
  if (tid == 0) lens[b] = red[0];
}

// ---------------- K1: pad x -> [65536,320] bf16 ----------------
__global__ __launch_bounds__(256) void k_xpad(const void* __restrict__ xraw,
                                              const int* __restrict__ flags,
                                              unsigned short* __restrict__ xp) {
  int id = blockIdx.x * 256 + threadIdx.x;
  int row = id / 40, seg = id % 40;
  int kbase = seg * 8;
  int bf = flags[0];
  unsigned short v[8];
  if (bf) {
    const unsigned short* x = (const unsigned short*)xraw;
#pragma unroll
    for (int i = 0; i < 8; ++i) {
      int k = kbase + i;
      v[i] = (k < D_) ? x[(size_t)row * D_ + k] : (unsigned short)0;
    }
  } else {
    const float* x = (const float*)xraw;
#pragma unroll
    for (int i = 0; i < 8; ++i) {
      int k = kbase + i;
      v[i] = (k < D_) ? f2b(x[(size_t)row * D_ + k]) : (unsigned short)0;
    }
  }
  uint4 o;
  o.x = (unsigned)v[0] | ((unsigned)v[1] << 16);
  o.y = (unsigned)v[2] | ((unsigned)v[3] << 16);
  o.z = (unsigned)v[4] | ((unsigned)v[5] << 16);
  o.w = (unsigned)v[6] | ((unsigned)v[7] << 16);
  *(uint4*)(xp + (size_t)row * KP + kbase) = o;
}

// ---------------- K2: pad k_{fwd,bwd} -> [2][320,960] bf16 ----------------
__global__ __launch_bounds__(256) void k_wpad(const void* __restrict__ kf,
                                              const void* __restrict__ kb,
                                              const int* __restrict__ flags,
                                              unsigned short* __restrict__ kp) {
  int id = blockIdx.x * 256 + threadIdx.x;
  if (id >= 2 * KP * NP) return;
  int dir = id / (KP * NP);
  int r = id % (KP * NP);
  int k = r / NP, n = r % NP;
  int bf = flags[0];
  unsigned short v = 0;
  if (k < D_ && n < NU) {
    size_t si = (size_t)k * NU + n;
    if (bf) v = ((const unsigned short*)(dir ? kb : kf))[si];
    else    v = f2b(((const float*)(dir ? kb : kf))[si]);
  }
  kp[id] = v;
}

// ---------------- K_prep: canonical rk (bf16), biases (f32), wfc, bfc ----------------
__global__ __launch_bounds__(256) void k_prep(const void* __restrict__ rkf,
                                              const void* __restrict__ rkb,
                                              const void* __restrict__ bfw,
                                              const void* __restrict__ bbw,
                                              const void* __restrict__ wfc,
                                              const void* __restrict__ bfc,
                                              const int* __restrict__ flags,
                                              unsigned short* __restrict__ rkc,   // [2][300][900]
                                              float* __restrict__ biasc,          // [2][2][900]
                                              unsigned short* __restrict__ wfcc,  // [600][300]
                                              float* __restrict__ bfcc) {         // [300]
  int i = blockIdx.x * 256 + threadIdx.x;
  int bf = flags[0];
  if (i < 2 * D_ * NU) {
    int dir = i / (D_ * NU), r = i % (D_ * NU);
    const void* src = dir ? rkb : rkf;
    rkc[i] = bf ? ((const unsigned short*)src)[r] : f2b(((const float*)src)[r]);
  }
  if (i < 2 * 2 * NU) {
    int dir = i / (2 * NU), r = i % (2 * NU);
    const void* src = dir ? bbw : bfw;
    biasc[i] = bf ? b2f_bits(((const unsigned short*)src)[r]) : ((const float*)src)[r];
  }
  if (i < 2 * U_ * U_) {
    wfcc[i] = bf ? ((const unsigned short*)wfc)[i] : f2b(((const float*)wfc)[i]);
  }
  if (i < U_) {
    bfcc[i] = bf ? b2f_bits(((const unsigned short*)bfc)[i]) : ((const float*)bfc)[i];
  }
}

// ---------------- K_bpack: rk -> per-wave MFMA B-fragment stream ----------------
// Wave w (of 8): waves 0-3 own 48 u-cols at U0=48w, 9 n-tiles (frag base 90w).
//                waves 4-7 own 32 u-cols at U0=192+32(w-4), 6 n-tiles (base 360+60(w-4)).
// n-tile nt = 3*b + g: u-block b (16 cols), gate g (z/r/h).
// frag f = base + kb*NT + nt; bpack[(dir*600+f)*512 + lane*8 + j] =
//   rk[k = kb*32 + (lane>>4)*8 + j][g*300 + U0 + b*16 + (lane&15)], 0 if pad.
__global__ __launch_bounds__(256) void k_bpack(const unsigned short* __restrict__ rkc,
                                               unsigned short* __restrict__ bpack) {
  int idx = blockIdx.x * 256 + threadIdx.x;
  const int total = 2 * FRAGS_PER_DIR * 512;
  if (idx >= total) return;
  int rem = idx;
  int j = rem & 7; rem >>= 3;
  int lane = rem & 63; rem >>= 6;
  int f = rem % FRAGS_PER_DIR;
  int dir = rem / FRAGS_PER_DIR;
  int w, fr, ntc;
  if (f < 360) { w = f / 90; fr = f - w * 90; ntc = 9; }
  else { int f2 = f - 360; w = 4 + f2 / 60; fr = f2 % 60; ntc = 6; }
  int kb = fr / ntc, nt = fr % ntc;
  int b = nt / 3, g = nt % 3;
  int l15 = lane & 15, quad = lane >> 4;
  int k = kb * 32 + quad * 8 + j;
  int U0 = (w < 4) ? w * 48 : 192 + (w - 4) * 32;
  int WUw = (w < 4) ? 48 : ((w < 7) ? 32 : 12);
  int local = b * 16 + l15;
  unsigned short v = 0;
  if (k < U_ && local < WUw) {
    int col = g * U_ + U0 + local;
    v = rkc[(size_t)dir * U_ * NU + (size_t)k * NU + col];
  }
  bpack[idx] = v;
}

// ---------------- K3: xp = x @ k + b_in, MFMA 16x16x32 bf16 ----------------
template <bool XPF32>
__global__ __launch_bounds__(256) void k_gemm(const unsigned short* __restrict__ xpad,
                                              const unsigned short* __restrict__ kpad,
                                              const float* __restrict__ biasc,
                                              void* __restrict__ xp_out) {
  __shared__ __align__(16) unsigned short As[64 * 40];
  __shared__ __align__(16) unsigned short Bs[64 * 40];  // transposed: [n][k]
  int tid = threadIdx.x;
  int wave = tid >> 6, lane = tid & 63;
  int m0 = blockIdx.x * 64, n0 = blockIdx.y * 64;
  int dir = blockIdx.z;
  const unsigned short* Bsrc = kpad + (size_t)dir * KP * NP;
  const float* bin = biasc + (size_t)dir * 2 * NU;

  floatx4 acc[4];
#pragma unroll
  for (int i = 0; i < 4; ++i) acc[i] = {0.f, 0.f, 0.f, 0.f};

  int arow = tid >> 2, aseg = tid & 3;
  int bk = tid & 31, bn8 = (tid >> 5) * 8;
  int fr = lane & 15, fq = lane >> 4;

  for (int kc = 0; kc < KP; kc += 32) {
    uint4 av = *(const uint4*)(xpad + (size_t)(m0 + arow) * KP + kc + aseg * 8);
    uint4 bv = *(const uint4*)(Bsrc + (size_t)(kc + bk) * NP + n0 + bn8);
    *(uint4*)(As + arow * 40 + aseg * 8) = av;
    unsigned short tmp[8];
    tmp[0] = bv.x & 0xffff; tmp[1] = bv.x >> 16;
    tmp[2] = bv.y & 0xffff; tmp[3] = bv.y >> 16;
    tmp[4] = bv.z & 0xffff; tmp[5] = bv.z >> 16;
    tmp[6] = bv.w & 0xffff; tmp[7] = bv.w >> 16;
#pragma unroll
    for (int i = 0; i < 8; ++i) Bs[(bn8 + i) * 40 + bk] = tmp[i];
    __syncthreads();
    short8 a = *(const short8*)(As + (wave * 16 + fr) * 40 + fq * 8);
#pragma unroll
    for (int nt = 0; nt < 4; ++nt) {
      short8 bfrag = *(const short8*)(Bs + (nt * 16 + fr) * 40 + fq * 8);
      acc[nt] = __builtin_amdgcn_mfma_f32_16x16x32_bf16(a, bfrag, acc[nt], 0, 0, 0);
    }
    __syncthreads();
  }
#pragma unroll
  for (int nt = 0; nt < 4; ++nt) {
    int col = n0 + nt * 16 + fr;
    if (col >= XPW) continue;
    float bi = (col < NU) ? bin[col] : 0.f;
#pragma unroll
    for (int r = 0; r < 4; ++r) {
      int m = m0 + wave * 16 + fq * 4 + r;
      float v = acc[nt][r] + bi;
      size_t idx = ((size_t)dir * 65536 + m) * XPW + col;
      if (XPF32) ((float*)xp_out)[idx] = v;
      else ((unsigned short*)xp_out)[idx] = f2b(v);
    }
  }
}

// ---------------- K4 helpers ----------------
// rp += h_hi @ B + h_lo @ B for this wave's column slice. B double-buffered
// from L2 (bpack stream), A fragments from LDS h.
template <int NTC>
__device__ __forceinline__ void phaseA(floatx4 (&acc)[4][9],
                                       const unsigned short* __restrict__ bp,
                                       const unsigned short (*sHi)[328],
                                       const unsigned short (*sLo)[328],
                                       int l15, int quad) {
  short8 bA[NTC], bB[NTC];
#pragma unroll
  for (int nt = 0; nt < NTC; ++nt)
    bA[nt] = *(const short8*)(bp + (size_t)nt * 512);
#pragma unroll 1
  for (int kb2 = 0; kb2 < KB_; kb2 += 2) {
    // prefetch kb2+1 into bB
#pragma unroll
    for (int nt = 0; nt < NTC; ++nt)
      bB[nt] = *(const short8*)(bp + ((size_t)(kb2 + 1) * NTC + nt) * 512);
    // compute kb2 with bA
#pragma unroll
    for (int mt = 0; mt < 4; ++mt) {
      const short8 ah = *(const short8*)&sHi[mt * 16 + l15][kb2 * 32 + quad * 8];
      const short8 al = *(const short8*)&sLo[mt * 16 + l15][kb2 * 32 + quad * 8];
#pragma unroll
      for (int nt = 0; nt < NTC; ++nt)
        acc[mt][nt] = __builtin_amdgcn_mfma_f32_16x16x32_bf16(ah, bA[nt], acc[mt][nt], 0, 0, 0);
#pragma unroll
      for (int nt = 0; nt < NTC; ++nt)
        acc[mt][nt] = __builtin_amdgcn_mfma_f32_16x16x32_bf16(al, bA[nt], acc[mt][nt], 0, 0, 0);
    }
    // prefetch kb2+2 into bA
    if (kb2 + 2 < KB_) {
#pragma unroll
      for (int nt = 0; nt < NTC; ++nt)
        bA[nt] = *(const short8*)(bp + ((size_t)(kb2 + 2) * NTC + nt) * 512);
    }
    // compute kb2+1 with bB
#pragma unroll
    for (int mt = 0; mt < 4; ++mt) {
      const short8 ah = *(const short8*)&sHi[mt * 16 + l15][(kb2 + 1) * 32 + quad * 8];
      const short8 al = *(const short8*)&sLo[mt * 16 + l15][(kb2 + 1) * 32 + quad * 8];
#pragma unroll
      for (int nt = 0; nt < NTC; ++nt)
        acc[mt][nt] = __builtin_amdgcn_mfma_f32_16x16x32_bf16(ah, bB[nt], acc[mt][nt], 0, 0, 0);
#pragma unroll
      for (int nt = 0; nt < NTC; ++nt)
        acc[mt][nt] = __builtin_amdgcn_mfma_f32_16x16x32_bf16(al, bB[nt], acc[mt][nt], 0, 0, 0);
    }
  }
}

// prefetch xp gate values for m-tile mt into X[b][g][r]
template <bool XPF32>
__device__ __forceinline__ void loadxp(float (&X)[3][3][4], const void* __restrict__ xp_all,
                                       int dir, int t, int mt, int U0, int WUw, int NB,
                                       int l15, int quad) {
  int uc[3];
#pragma unroll
  for (int b = 0; b < 3; ++b) {
    int local = b * 16 + l15;
    uc[b] = (local < WUw) ? (U0 + local) : 0;   // clamped safe column
  }
#pragma unroll
  for (int r = 0; r < 4; ++r) {
    int row = mt * 16 + quad * 4 + r;
    size_t ro = ((size_t)dir * 65536 + (size_t)row * T_ + t) * XPW;
    if (XPF32) {
      const float* xr = (const float*)xp_all + ro;
#pragma unroll
      for (int b = 0; b < 3; ++b) {
        if (b >= NB) continue;
        X[b][0][r] = xr[uc[b]];
        X[b][1][r] = xr[U_ + uc[b]];
        X[b][2][r] = xr[2 * U_ + uc[b]];
      }
    } else {
      const unsigned short* xr = (const unsigned short*)xp_all + ro;
#pragma unroll
      for (int b = 0; b < 3; ++b) {
        if (b >= NB) continue;
        X[b][0][r] = b2f_bits(xr[uc[b]]);
        X[b][1][r] = b2f_bits(xr[U_ + uc[b]]);
        X[b][2][r] = b2f_bits(xr[2 * U_ + uc[b]]);
      }
    }
  }
}

// epilogue for m-tile MT: gates + h update + y store. All values this lane
// needs (z/r/h rp) are in its own acc regs (gate-interleaved packing).
template <int MT>
__device__ __forceinline__ void epi_mt(floatx4 (&acc)[4][9], float (&X)[3][3][4],
                                       unsigned short (*sHi)[328], unsigned short (*sLo)[328],
                                       const float* __restrict__ sBias, const int* __restrict__ sLen,
                                       int t, int dir, int U0, int WUw, int NB,
                                       int l15, int quad, int obf,
                                       unsigned short* __restrict__ out16, float* __restrict__ out32) {
  float bzv[3], brv[3], bhv[3]; int ucv[3]; bool cvv[3];
#pragma unroll
  for (int b = 0; b < 3; ++b) {
    int local = b * 16 + l15;
    bool cv = (b < NB) && (local < WUw);
    int uc = cv ? (U0 + local) : 0;
    cvv[b] = cv; ucv[b] = uc;
    bzv[b] = sBias[uc]; brv[b] = sBias[U_ + uc]; bhv[b] = sBias[2 * U_ + uc];
  }
#pragma unroll
  for (int r = 0; r < 4; ++r) {
    int row = MT * 16 + quad * 4 + r;
    bool m = (t < sLen[row]);
#pragma unroll
    for (int b = 0; b < 3; ++b) {
      if (b >= NB) continue;
      int uc = ucv[b];
      float z  = 1.f / (1.f + __expf(-(X[b][0][r] + acc[MT][3 * b + 0][r] + bzv[b])));
      float rg = 1.f / (1.f + __expf(-(X[b][1][r] + acc[MT][3 * b + 1][r] + brv[b])));
      float hh = tanhf(X[b][2][r] + rg * (acc[MT][3 * b + 2][r] + bhv[b]));
      float hold = b2f_bits(sHi[row][uc]) + b2f_bits(sLo[row][uc]);
      float hn = z * hold + (1.f - z) * hh;
      float hw = m ? hn : hold;
      if (cvv[b]) {
        float y = m ? hn : 0.f;
        size_t ob = ((size_t)row * T_ + t) * 600 + (size_t)dir * U_ + (size_t)uc;
        if (obf) out16[ob] = f2b(y); else out32[ob] = y;
        unsigned short hib = f2b(hw);
        sHi[row][uc] = hib;
        sLo[row][uc] = f2b(hw - b2f_bits(hib));
      }
    }
  }
}

// ---------------- K4: GRU scan, one workgroup per direction ----------------
template <bool XPF32>
__global__ __launch_bounds__(512, 2) void k_scan(const unsigned short* __restrict__ bpack,
                                                 const float* __restrict__ biasc,
                                                 const void* __restrict__ xp_all,
                                                 const int* __restrict__ lens,
                                                 const int* __restrict__ flags,
                                                 float* __restrict__ hfin,          // [2][64][304]
                                                 void* __restrict__ outraw) {
  __shared__ unsigned short sHi[64][328];   // row stride 328 shorts: bank-friendly, 16B rows
  __shared__ unsigned short sLo[64][328];
  __shared__ float sBias[912];              // b_rec z|r|h
  __shared__ int sLen[64];

  const int tid = threadIdx.x;
  const int dir = blockIdx.x;
  const int wave = tid >> 6, lane = tid & 63;
  const int l15 = lane & 15, quad = lane >> 4;
  const int obf = flags[0];
  unsigned short* out16 = (unsigned short*)outraw;
  float* out32 = (float*)outraw;

  // init LDS: zero h, copy bias + lens
  {
    unsigned int* p0 = (unsigned int*)&sHi[0][0];
    unsigned int* p1 = (unsigned int*)&sLo[0][0];
    for (int i = tid; i < 64 * 328 / 2; i += 512) { p0[i] = 0u; p1[i] = 0u; }
    const float* brec = biasc + (size_t)dir * 2 * NU + NU;
    for (int i = tid; i < NU; i += 512) sBias[i] = brec[i];
    if (tid < 64) sLen[tid] = lens[tid];
  }
  __syncthreads();

  const int NB  = (wave < 4) ? 3 : 2;
  const int U0  = (wave < 4) ? wave * 48 : 192 + (wave - 4) * 32;
  const int WUw = (wave < 4) ? 48 : ((wave < 7) ? 32 : 12);
  const int FB  = (wave < 4) ? wave * 90 : 360 + (wave - 4) * 60;
  const unsigned short* bp = bpack + ((size_t)dir * FRAGS_PER_DIR + FB) * 512 + (size_t)lane * 8;

  floatx4 acc[4][9];

#pragma unroll 1
  for (int s = 0; s < T_; ++s) {
    const int t = dir ? (T_ - 1 - s) : s;
#pragma unroll
    for (int mt = 0; mt < 4; ++mt)
#pragma unroll
      for (int nt = 0; nt < 9; ++nt) acc[mt][nt] = {0.f, 0.f, 0.f, 0.f};

    if (wave < 4) phaseA<9>(acc, bp, sHi, sLo, l15, quad);
    else          phaseA<6>(acc, bp, sHi, sLo, l15, quad);

    float xgA[3][3][4], xgB[3][3][4];
    loadxp<XPF32>(xgA, xp_all, dir, t, 0, U0, WUw, NB, l15, quad);
    __syncthreads();   // all h reads of this step done
    loadxp<XPF32>(xgB, xp_all, dir, t, 1, U0, WUw, NB, l15, quad);
    epi_mt<0>(acc, xgA, sHi, sLo, sBias, sLen, t, dir, U0, WUw, NB, l15, quad, obf, out16, out32);
    loadxp<XPF32>(xgA, xp_all, dir, t, 2, U0, WUw, NB, l15, quad);
    epi_mt<1>(acc, xgB, sHi, sLo, sBias, sLen, t, dir, U0, WUw, NB, l15, quad, obf, out16, out32);
    loadxp<XPF32>(xgB, xp_all, dir, t, 3, U0, WUw, NB, l15, quad);
    epi_mt<2>(acc, xgA, sHi, sLo, sBias, sLen, t, dir, U0, WUw, NB, l15, quad, obf, out16, out32);
    epi_mt<3>(acc, xgB, sHi, sLo, sBias, sLen, t, dir, U0, WUw, NB, l15, quad, obf, out16, out32);
    __syncthreads();   // h writes visible before next step's reads
  }

  // final state from LDS
  {
    int row = tid >> 3;
    for (int u = (tid & 7); u < U_; u += 8)
      hfin[((size_t)dir * B_ + row) * 304 + u] = b2f_bits(sHi[row][u]) + b2f_bits(sLo[row][u]);
  }
}

// ---------------- K5: state = relu(concat(h_f,h_b) @ w_fc + b_fc) ----------------
__global__ __launch_bounds__(320) void k_state(const float* __restrict__ hfin,
                                               const unsigned short* __restrict__ wfcc,
                                               const float* __restrict__ bfcc,
                                               const int* __restrict__ flags,
                                               void* __restrict__ outraw) {
  int b = blockIdx.x, u = threadIdx.x;
  if (u >= U_) return;
  int obf = flags[0];
  float acc = bfcc[u];
  const float* hf = hfin + (size_t)b * 304;
  const float* hb = hfin + ((size_t)B_ + b) * 304;
  for (int k = 0; k < U_; ++k) acc = fmaf(hf[k], b2f_bits(wfcc[(size_t)k * U_ + u]), acc);
  for (int k = 0; k < U_; ++k) acc = fmaf(hb[k], b2f_bits(wfcc[(size_t)(U_ + k) * U_ + u]), acc);
  float v = fmaxf(acc, 0.f);
  size_t oi = (size_t)B_ * T_ * 600 + (size_t)b * U_ + u;
  if (obf) ((unsigned short*)outraw)[oi] = f2b(v);
  else     ((float*)outraw)[oi] = v;
}

extern "C" void kernel_launch(void* const* d_in, const int* in_sizes, int n_in,
                              void* d_out, int out_size, void* d_ws, size_t ws_size,
                              hipStream_t stream) {
  const void* x    = d_in[0];
  const void* mask = d_in[1];
  const void* kf   = d_in[2];
  const void* rkf  = d_in[3];
  const void* bfw  = d_in[4];
  const void* kb   = d_in[5];
  const void* rkb  = d_in[6];
  const void* bbw  = d_in[7];
  const void* wfc  = d_in[8];
  const void* bfc  = d_in[9];

  char* ws = (char*)d_ws;
  size_t off = 0;
  auto alloc = [&](size_t bytes) { void* p = ws + off; off += (bytes + 255) & ~(size_t)255; return p; };
  int* flags            = (int*)alloc(256);
  int* lens             = (int*)alloc(256);
  unsigned short* xpad  = (unsigned short*)alloc((size_t)65536 * KP * 2);
  unsigned short* kpad  = (unsigned short*)alloc((size_t)2 * KP * NP * 2);
  unsigned short* rkc   = (unsigned short*)alloc((size_t)2 * D_ * NU * 2);
  unsigned short* bpack = (unsigned short*)alloc((size_t)2 * FRAGS_PER_DIR * 512 * 2);
  float* biasc          = (float*)alloc((size_t)2 * 2 * NU * 4);
  unsigned short* wfcc  = (unsigned short*)alloc((size_t)2 * U_ * U_ * 2);
  float* bfcc           = (float*)alloc((size_t)U_ * 4);
  float* hfin           = (float*)alloc((size_t)2 * B_ * 304 * 4);
  void* xp = (void*)(ws + off);
  size_t need_f32 = off + (size_t)2 * 65536 * XPW * 4;
  bool xpf32 = ws_size >= need_f32;

  k_detect<<<dim3(1), dim3(64), 0, stream>>>((const unsigned int*)x, (const unsigned char*)mask, flags);
  k_lengths<<<dim3(B_), dim3(256), 0, stream>>>((const unsigned char*)mask, flags, lens);
  k_xpad<<<dim3(65536 * 40 / 256), dim3(256), 0, stream>>>(x, flags, xpad);
  k_wpad<<<dim3((2 * KP * NP + 255) / 256), dim3(256), 0, stream>>>(kf, kb, flags, kpad);
  k_prep<<<dim3((2 * D_ * NU + 255) / 256), dim3(256), 0, stream>>>(rkf, rkb, bfw, bbw, wfc, bfc,
                                                                    flags, rkc, biasc, wfcc, bfcc);
  k_bpack<<<dim3((2 * FRAGS_PER_DIR * 512 + 255) / 256), dim3(256), 0, stream>>>(rkc, bpack);
  if (xpf32) {
    k_gemm<true><<<dim3(1024, 15, 2), dim3(256), 0, stream>>>(xpad, kpad, biasc, xp);
    k_scan<true><<<dim3(2), dim3(512), 0, stream>>>(bpack, biasc, xp, lens, flags, hfin, d_out);
  } else {
    k_gemm<false><<<dim3(1024, 15, 2), dim3(256), 0, stream>>>(xpad, kpad, biasc, xp);
    k_scan<false><<<dim3(2), dim3(512), 0, stream>>>(bpack, biasc, xp, lens, flags, hfin, d_out);
  }
  k_state<<<dim3(B_), dim3(320), 0, stream>>>(hfin, wfcc, bfcc, flags, d_out);
}

// Round 2
// 14546.468 us; speedup vs baseline: 2.9158x; 2.9158x over previous
//
#include <hip/hip_runtime.h>
#include <hip/hip_bf16.h>

// Bidirectional GRU encoder, B=64 T=1024 D=300 U=300.
// Round 6: batch-split scan. The B=64 rows are independent recurrences, so
// split batch (not columns): 4 WGs/direction x 16 batch rows each, h-slice
// (16x320 bf16 hi/lo ~ 21 KB) in the WG's own LDS, ZERO cross-WG sync
// (2 intra-CU __syncthreads per step). Per CU/step: ~1140 MFMA (~2.0us),
// B-stream 570 KB from L2 with 2/10 K-blocks LDS-resident (-> 456 KB,
// ~3.4us, double-buffered under MFMA). Gate-interleaved B packing puts
// each lane's z/r/h in its own acc regs -> in-register epilogue, hold
// state in registers (exclusive (row,u) ownership per lane).

#define B_   64
#define T_   1024
#define D_   300
#define U_   300
#define NU   900      // 3U
#define KP   320      // padded K for input GEMM
#define NP   960      // padded N width of k_pad
#define XPW  912      // xp row stride (elements)
#define KB_  10       // K blocks of 32 (320/32)
#define KRES 2        // K blocks LDS-resident in scan
#define HSP  328      // h LDS row stride (shorts): 656B = 2-way-free bank stride
#define FRAGS_PER_DIR 570   // 3 waves*90 + 5 waves*60
#define NRESF 114           // resident frags per dir (3*18 + 5*12)
#define NWGM 4              // m-groups (16 rows each)

typedef short short8 __attribute__((ext_vector_type(8)));
typedef float floatx4 __attribute__((ext_vector_type(4)));

__device__ __forceinline__ float b2f_bits(unsigned short u) {
  union { unsigned int i; float f; } v; v.i = ((unsigned int)u) << 16; return v.f;
}
__device__ __forceinline__ unsigned short f2b(float f) {
  __hip_bfloat16 h = __float2bfloat16(f);  // RNE
  return *reinterpret_cast<unsigned short*>(&h);
}

// ---------------- K_detect: input dtype + mask dtype flags ----------------
__global__ __launch_bounds__(64) void k_detect(const unsigned int* __restrict__ xw,
                                               const unsigned char* __restrict__ mb,
                                               int* __restrict__ flags) {
  __shared__ int red[64];
  int tid = threadIdx.x;
  int hits = 0;
  for (int i = tid; i < 2048; i += 64) {
    unsigned int lo = xw[i] & 0xFFFFu;
    int e = (int)((lo >> 7) & 0xFF);
    if (e >= 105 && e <= 135) hits++;   // plausible bf16 exponent for N(0,1)
  }
  red[tid] = hits;
  __syncthreads();
  if (tid == 0) {
    int s = 0;
    for (int i = 0; i < 64; ++i) s += red[i];
    flags[0] = (s >= 1024) ? 1 : 0;
    unsigned char b0 = mb[0], b1 = mb[1];
    flags[1] = (b1 == 0) ? 0 : ((b0 == 1 && b1 == 1) ? 1 : 2);
  }
}

// ---------------- K0: lengths from mask ----------------
__global__ __launch_bounds__(256) void k_lengths(const unsigned char* __restrict__ mraw,
                                                 const int* __restrict__ flags,
                                                 int* __restrict__ lens) {
  __shared__ int red[256];
  int b = blockIdx.x, tid = threadIdx.x;
  int mt = flags[1];
  int s = 0;
  if (mt == 0) {
    const int* m = (const int*)mraw;
    for (int t = tid; t < T_; t += 256) s += m[(size_t)b * T_ + t] ? 1 : 0;
  } else if (mt == 1) {
    for (int t = tid; t < T_; t += 256) s += mraw[(size_t)b * T_ + t] ? 1 : 0;
  } else {
    const unsigned short* m = (const unsigned short*)mraw;
    for (int t = tid; t < T_; t += 256) s += m[(size_t)b * T_ + t] ? 1 : 0;
  }
  red[tid] = s; __syncthreads();
  for (int off = 128; off > 0; off >>= 1) {
    if (tid < off) red[tid] += red[tid + off];
    __syncthreads();
  }
  if (tid == 0) lens[b] = red[0];
}

// ---------------- K1: pad x -> [65536,320] bf16 ----------------
__global__ __launch_bounds__(256) void k_xpad(const void* __restrict__ xraw,
                                              const int* __restrict__ flags,
                                              unsigned short* __restrict__ xp) {
  int id = blockIdx.x * 256 + threadIdx.x;
  int row = id / 40, seg = id % 40;
  int kbase = seg * 8;
  int bf = flags[0];
  unsigned short v[8];
  if (bf) {
    const unsigned short* x = (const unsigned short*)xraw;
#pragma unroll
    for (int i = 0; i < 8; ++i) {
      int k = kbase + i;
      v[i] = (k < D_) ? x[(size_t)row * D_ + k] : (unsigned short)0;
    }
  } else {
    const float* x = (const float*)xraw;
#pragma unroll
    for (int i = 0; i < 8; ++i) {
      int k = kbase + i;
      v[i] = (k < D_) ? f2b(x[(size_t)row * D_ + k]) : (unsigned short)0;
    }
  }
  uint4 o;
  o.x = (unsigned)v[0] | ((unsigned)v[1] << 16);
  o.y = (unsigned)v[2] | ((unsigned)v[3] << 16);
  o.z = (unsigned)v[4] | ((unsigned)v[5] << 16);
  o.w = (unsigned)v[6] | ((unsigned)v[7] << 16);
  *(uint4*)(xp + (size_t)row * KP + kbase) = o;
}

// ---------------- K2: pad k_{fwd,bwd} -> [2][320,960] bf16 ----------------
__global__ __launch_bounds__(256) void k_wpad(const void* __restrict__ kf,
                                              const void* __restrict__ kb,
                                              const int* __restrict__ flags,
                                              unsigned short* __restrict__ kp) {
  int id = blockIdx.x * 256 + threadIdx.x;
  if (id >= 2 * KP * NP) return;
  int dir = id / (KP * NP);
  int r = id % (KP * NP);
  int k = r / NP, n = r % NP;
  int bf = flags[0];
  unsigned short v = 0;
  if (k < D_ && n < NU) {
    size_t si = (size_t)k * NU + n;
    if (bf) v = ((const unsigned short*)(dir ? kb : kf))[si];
    else    v = f2b(((const float*)(dir ? kb : kf))[si]);
  }
  kp[id] = v;
}

// ---------------- K_prep: canonical rk (bf16), biases (f32), wfc, bfc ----------------
__global__ __launch_bounds__(256) void k_prep(const void* __restrict__ rkf,
                                              const void* __restrict__ rkb,
                                              const void* __restrict__ bfw,
                                              const void* __restrict__ bbw,
                                              const void* __restrict__ wfc,
                                              const void* __restrict__ bfc,
                                              const int* __restrict__ flags,
                                              unsigned short* __restrict__ rkc,   // [2][300][900]
                                              float* __restrict__ biasc,          // [2][2][900]
                                              unsigned short* __restrict__ wfcc,  // [600][300]
                                              float* __restrict__ bfcc) {         // [300]
  int i = blockIdx.x * 256 + threadIdx.x;
  int bf = flags[0];
  if (i < 2 * D_ * NU) {
    int dir = i / (D_ * NU), r = i % (D_ * NU);
    const void* src = dir ? rkb : rkf;
    rkc[i] = bf ? ((const unsigned short*)src)[r] : f2b(((const float*)src)[r]);
  }
  if (i < 2 * 2 * NU) {
    int dir = i / (2 * NU), r = i % (2 * NU);
    const void* src = dir ? bbw : bfw;
    biasc[i] = bf ? b2f_bits(((const unsigned short*)src)[r]) : ((const float*)src)[r];
  }
  if (i < 2 * U_ * U_) {
    wfcc[i] = bf ? ((const unsigned short*)wfc)[i] : f2b(((const float*)wfc)[i]);
  }
  if (i < U_) {
    bfcc[i] = bf ? b2f_bits(((const unsigned short*)bfc)[i]) : ((const float*)bfc)[i];
  }
}

// ---------------- K_bpack: rk -> per-wave MFMA B-fragment stream ----------------
// Waves 0-2 own 3 u-blocks (ub0 = 3w), waves 3-7 own 2 (ub0 = 9+2(w-3)).
// 19 u-blocks of 16 cols cover u 0..303 (300..303 zero-padded).
// n-tile nt = lb*3 + g (local block lb, gate g in z/r/h order).
// frag f = FB(w) + kb*NTC + nt; bpack[(dir*570+f)*512 + lane*8 + j] =
//   rk[k = kb*32 + (lane>>4)*8 + j][g*300 + (ub0+lb)*16 + (lane&15)], 0 if pad.
__global__ __launch_bounds__(256) void k_bpack(const unsigned short* __restrict__ rkc,
                                               unsigned short* __restrict__ bpack) {
  int idx = blockIdx.x * 256 + threadIdx.x;
  const int total = 2 * FRAGS_PER_DIR * 512;
  if (idx >= total) return;
  int rem = idx;
  int j = rem & 7; rem >>= 3;
  int lane = rem & 63; rem >>= 6;
  int f = rem % FRAGS_PER_DIR;
  int dir = rem / FRAGS_PER_DIR;
  int w, fr, ntc;
  if (f < 270) { w = f / 90; fr = f - w * 90; ntc = 9; }
  else { int f2 = f - 270; w = 3 + f2 / 60; fr = f2 % 60; ntc = 6; }
  int kb = fr / ntc, nt = fr % ntc;
  int lb = nt / 3, g = nt % 3;
  int ub0 = (w < 3) ? w * 3 : 9 + (w - 3) * 2;
  int l15 = lane & 15, quad = lane >> 4;
  int k = kb * 32 + quad * 8 + j;
  int u = (ub0 + lb) * 16 + l15;
  unsigned short v = 0;
  if (k < U_ && u < U_) {
    v = rkc[(size_t)dir * U_ * NU + (size_t)k * NU + (size_t)g * U_ + u];
  }
  bpack[idx] = v;
}

// ---------------- K3: xp = x @ k + b_in, MFMA 16x16x32 bf16 ----------------
template <bool XPF32>
__global__ __launch_bounds__(256) void k_gemm(const unsigned short* __restrict__ xpad,
                                              const unsigned short* __restrict__ kpad,
                                              const float* __restrict__ biasc,
                                              void* __restrict__ xp_out) {
  __shared__ __align__(16) unsigned short As[64 * 40];
  __shared__ __align__(16) unsigned short Bs[64 * 40];  // transposed: [n][k]
  int tid = threadIdx.x;
  int wave = tid >> 6, lane = tid & 63;
  int m0 = blockIdx.x * 64, n0 = blockIdx.y * 64;
  int dir = blockIdx.z;
  const unsigned short* Bsrc = kpad + (size_t)dir * KP * NP;
  const float* bin = biasc + (size_t)dir * 2 * NU;

  floatx4 acc[4];
#pragma unroll
  for (int i = 0; i < 4; ++i) acc[i] = {0.f, 0.f, 0.f, 0.f};

  int arow = tid >> 2, aseg = tid & 3;
  int bk = tid & 31, bn8 = (tid >> 5) * 8;
  int fr = lane & 15, fq = lane >> 4;

  for (int kc = 0; kc < KP; kc += 32) {
    uint4 av = *(const uint4*)(xpad + (size_t)(m0 + arow) * KP + kc + aseg * 8);
    uint4 bv = *(const uint4*)(Bsrc + (size_t)(kc + bk) * NP + n0 + bn8);
    *(uint4*)(As + arow * 40 + aseg * 8) = av;
    unsigned short tmp[8];
    tmp[0] = bv.x & 0xffff; tmp[1] = bv.x >> 16;
    tmp[2] = bv.y & 0xffff; tmp[3] = bv.y >> 16;
    tmp[4] = bv.z & 0xffff; tmp[5] = bv.z >> 16;
    tmp[6] = bv.w & 0xffff; tmp[7] = bv.w >> 16;
#pragma unroll
    for (int i = 0; i < 8; ++i) Bs[(bn8 + i) * 40 + bk] = tmp[i];
    __syncthreads();
    short8 a = *(const short8*)(As + (wave * 16 + fr) * 40 + fq * 8);
#pragma unroll
    for (int nt = 0; nt < 4; ++nt) {
      short8 bfrag = *(const short8*)(Bs + (nt * 16 + fr) * 40 + fq * 8);
      acc[nt] = __builtin_amdgcn_mfma_f32_16x16x32_bf16(a, bfrag, acc[nt], 0, 0, 0);
    }
    __syncthreads();
  }
#pragma unroll
  for (int nt = 0; nt < 4; ++nt) {
    int col = n0 + nt * 16 + fr;
    if (col >= XPW) continue;
    float bi = (col < NU) ? bin[col] : 0.f;
#pragma unroll
    for (int r = 0; r < 4; ++r) {
      int m = m0 + wave * 16 + fq * 4 + r;
      float v = acc[nt][r] + bi;
      size_t idx = ((size_t)dir * 65536 + m) * XPW + col;
      if (XPF32) ((float*)xp_out)[idx] = v;
      else ((unsigned short*)xp_out)[idx] = f2b(v);
    }
  }
}

// ---------------- K4 helper: one step's MFMA phase for one wave ----------------
// acc[nt] += h_hi @ B + h_lo @ B. kb 0..KRES-1 from LDS-resident sB,
// kb KRES..9 streamed from L2 (double-buffered). A frags from LDS h.
template <int NTC>
__device__ __forceinline__ void phase(floatx4 (&acc)[9],
                                      const unsigned short* __restrict__ bp,
                                      const unsigned short* __restrict__ sBw,
                                      const unsigned short (*sHi)[HSP],
                                      const unsigned short (*sLo)[HSP],
                                      int l15, int quad) {
  short8 bA[NTC], bB[NTC];
  // issue stream loads for kb=KRES, KRES+1 first (covered by resident compute)
#pragma unroll
  for (int nt = 0; nt < NTC; ++nt)
    bA[nt] = *(const short8*)(bp + ((size_t)(KRES * NTC + nt)) * 512);
#pragma unroll
  for (int nt = 0; nt < NTC; ++nt)
    bB[nt] = *(const short8*)(bp + ((size_t)((KRES + 1) * NTC + nt)) * 512);
  // LDS-resident kb = 0..KRES-1
#pragma unroll
  for (int kb = 0; kb < KRES; ++kb) {
    short8 ah = *(const short8*)&sHi[l15][kb * 32 + quad * 8];
    short8 al = *(const short8*)&sLo[l15][kb * 32 + quad * 8];
#pragma unroll
    for (int nt = 0; nt < NTC; ++nt) {
      short8 b = *(const short8*)(sBw + ((size_t)(kb * NTC + nt)) * 512);
      acc[nt] = __builtin_amdgcn_mfma_f32_16x16x32_bf16(ah, b, acc[nt], 0, 0, 0);
      acc[nt] = __builtin_amdgcn_mfma_f32_16x16x32_bf16(al, b, acc[nt], 0, 0, 0);
    }
  }
  // streamed kb = KRES..KB_-1, double-buffered
#pragma unroll
  for (int kb = KRES; kb < KB_; kb += 2) {
    {
      short8 ah = *(const short8*)&sHi[l15][kb * 32 + quad * 8];
      short8 al = *(const short8*)&sLo[l15][kb * 32 + quad * 8];
#pragma unroll
      for (int nt = 0; nt < NTC; ++nt) {
        acc[nt] = __builtin_amdgcn_mfma_f32_16x16x32_bf16(ah, bA[nt], acc[nt], 0, 0, 0);
        acc[nt] = __builtin_amdgcn_mfma_f32_16x16x32_bf16(al, bA[nt], acc[nt], 0, 0, 0);
      }
      if (kb + 2 < KB_) {
#pragma unroll
        for (int nt = 0; nt < NTC; ++nt)
          bA[nt] = *(const short8*)(bp + ((size_t)((kb + 2) * NTC + nt)) * 512);
      }
    }
    {
      short8 ah = *(const short8*)&sHi[l15][(kb + 1) * 32 + quad * 8];
      short8 al = *(const short8*)&sLo[l15][(kb + 1) * 32 + quad * 8];
#pragma unroll
      for (int nt = 0; nt < NTC; ++nt) {
        acc[nt] = __builtin_amdgcn_mfma_f32_16x16x32_bf16(ah, bB[nt], acc[nt], 0, 0, 0);
        acc[nt] = __builtin_amdgcn_mfma_f32_16x16x32_bf16(al, bB[nt], acc[nt], 0, 0, 0);
      }
      if (kb + 3 < KB_) {
#pragma unroll
        for (int nt = 0; nt < NTC; ++nt)
          bB[nt] = *(const short8*)(bp + ((size_t)((kb + 3) * NTC + nt)) * 512);
      }
    }
  }
}

// ---------------- K4: GRU scan, 4 WGs x 16 batch rows per direction ----------------
template <bool XPF32>
__global__ __launch_bounds__(512) void k_scan(const unsigned short* __restrict__ bpack,
                                              const float* __restrict__ biasc,
                                              const void* __restrict__ xp_all,
                                              const int* __restrict__ lens,
                                              const int* __restrict__ flags,
                                              float* __restrict__ hfin,          // [2][64][304]
                                              void* __restrict__ outraw) {
  __shared__ unsigned short sHi[16][HSP];
  __shared__ unsigned short sLo[16][HSP];
  __shared__ __align__(16) unsigned short sB[NRESF * 512];

  const int tid = threadIdx.x;
  const int mg = blockIdx.x;        // m-group: batch rows 16mg..16mg+15
  const int dir = blockIdx.y;
  const int wave = tid >> 6, lane = tid & 63;
  const int l15 = lane & 15, quad = lane >> 4;
  const int obf = flags[0];
  unsigned short* out16 = (unsigned short*)outraw;
  float* out32 = (float*)outraw;

  const int NBLK = (wave < 3) ? 3 : 2;
  const int NTCw = NBLK * 3;
  const int UB0w = (wave < 3) ? wave * 3 : 9 + (wave - 3) * 2;
  const int FB   = (wave < 3) ? wave * 90 : 270 + (wave - 3) * 60;
  const int RB   = (wave < 3) ? wave * 18 : 54 + (wave - 3) * 12;

  // zero h
  {
    unsigned int* p0 = (unsigned int*)&sHi[0][0];
    unsigned int* p1 = (unsigned int*)&sLo[0][0];
    for (int i = tid; i < 16 * HSP / 2; i += 512) { p0[i] = 0u; p1[i] = 0u; }
  }
  // copy this wave's resident B frags (kb < KRES) into LDS
  {
    const unsigned short* src = bpack + ((size_t)dir * FRAGS_PER_DIR + FB) * 512 + lane * 8;
    unsigned short* dst = sB + (size_t)RB * 512 + lane * 8;
    for (int j = 0; j < KRES * NTCw; ++j)
      *(uint4*)(dst + (size_t)j * 512) = *(const uint4*)(src + (size_t)j * 512);
  }

  // per-lane epilogue ownership: rows quad*4+r, u-cols (UB0w+lb)*16 + l15
  int ucl[3]; bool cv[3];
  float bz[3], brg[3], bh[3];
  {
    const float* brec = biasc + (size_t)dir * 2 * NU + NU;
#pragma unroll
    for (int lb = 0; lb < 3; ++lb) {
      int u = (UB0w + lb) * 16 + l15;
      bool v = (lb < NBLK) && (u < U_);
      cv[lb] = v;
      ucl[lb] = v ? u : 0;
      bz[lb] = brec[ucl[lb]]; brg[lb] = brec[U_ + ucl[lb]]; bh[lb] = brec[2 * U_ + ucl[lb]];
    }
  }
  int mylen[4];
#pragma unroll
  for (int r = 0; r < 4; ++r) mylen[r] = lens[mg * 16 + quad * 4 + r];
  float hold[3][4];
#pragma unroll
  for (int lb = 0; lb < 3; ++lb)
#pragma unroll
    for (int r = 0; r < 4; ++r) hold[lb][r] = 0.f;

  __syncthreads();

  const unsigned short* bp = bpack + ((size_t)dir * FRAGS_PER_DIR + FB) * 512 + (size_t)lane * 8;
  const unsigned short* sBw = sB + (size_t)RB * 512 + (size_t)lane * 8;

#pragma unroll 1
  for (int s = 0; s < T_; ++s) {
    const int t = dir ? (T_ - 1 - s) : s;

    floatx4 acc[9];
#pragma unroll
    for (int i = 0; i < 9; ++i) acc[i] = {0.f, 0.f, 0.f, 0.f};
    if (wave < 3) phase<9>(acc, bp, sBw, sHi, sLo, l15, quad);
    else          phase<6>(acc, bp, sBw, sHi, sLo, l15, quad);

    // xp gate values for this step (issued before barrier; used after)
    float X[3][3][4];
    {
      size_t dbase = (size_t)dir * 65536;
#pragma unroll
      for (int r = 0; r < 4; ++r) {
        size_t ro = (dbase + (size_t)(mg * 16 + quad * 4 + r) * T_ + t) * XPW;
        if (XPF32) {
          const float* xr = (const float*)xp_all + ro;
#pragma unroll
          for (int lb = 0; lb < 3; ++lb) {
            X[lb][0][r] = xr[ucl[lb]];
            X[lb][1][r] = xr[U_ + ucl[lb]];
            X[lb][2][r] = xr[2 * U_ + ucl[lb]];
          }
        } else {
          const unsigned short* xr = (const unsigned short*)xp_all + ro;
#pragma unroll
          for (int lb = 0; lb < 3; ++lb) {
            X[lb][0][r] = b2f_bits(xr[ucl[lb]]);
            X[lb][1][r] = b2f_bits(xr[U_ + ucl[lb]]);
            X[lb][2][r] = b2f_bits(xr[2 * U_ + ucl[lb]]);
          }
        }
      }
    }

    __syncthreads();   // all A-reads of h done before h is overwritten

    // epilogue: gates + h update for owned (row, u). hold in regs.
#pragma unroll
    for (int r = 0; r < 4; ++r) {
      const int row = quad * 4 + r;
      const bool m = (t < mylen[r]);
      const size_t ob = ((size_t)(mg * 16 + row) * T_ + t) * 600 + (size_t)dir * U_;
#pragma unroll
      for (int lb = 0; lb < 3; ++lb) {
        float z  = 1.f / (1.f + __expf(-(X[lb][0][r] + acc[lb * 3 + 0][r] + bz[lb])));
        float rg = 1.f / (1.f + __expf(-(X[lb][1][r] + acc[lb * 3 + 1][r] + brg[lb])));
        float hh = tanhf(X[lb][2][r] + rg * (acc[lb * 3 + 2][r] + bh[lb]));
        float hn = z * hold[lb][r] + (1.f - z) * hh;
        float hw = m ? hn : hold[lb][r];
        hold[lb][r] = hw;
        if (cv[lb]) {
          float y = m ? hn : 0.f;
          if (obf) out16[ob + ucl[lb]] = f2b(y); else out32[ob + ucl[lb]] = y;
          unsigned short hib = f2b(hw);
          sHi[row][ucl[lb]] = hib;
          sLo[row][ucl[lb]] = f2b(hw - b2f_bits(hib));
        }
      }
    }
    __syncthreads();   // h writes visible before next step's A-reads
  }

  // final state straight from registers
#pragma unroll
  for (int lb = 0; lb < 3; ++lb) {
    if (!cv[lb]) continue;
#pragma unroll
    for (int r = 0; r < 4; ++r)
      hfin[((size_t)dir * B_ + mg * 16 + quad * 4 + r) * 304 + ucl[lb]] = hold[lb][r];
  }
}

// ---------------- K5: state = relu(concat(h_f,h_b) @ w_fc + b_fc) ----------------
__global__ __launch_bounds__(320) void k_state(const float* __restrict__ hfin,
                                               const unsigned short* __restrict__ wfcc,
                                               const float* __restrict__ bfcc,
                                               const int* __restrict__ flags,
                                               void* __restrict__ outraw) {
  int b = blockIdx.x, u = threadIdx.x;
  if (u >= U_) return;
  int obf = flags[0];
  float acc = bfcc[u];
  const float* hf = hfin + (size_t)b * 304;
  const float* hb = hfin + ((size_t)B_ + b) * 304;
  for (int k = 0; k < U_; ++k) acc = fmaf(hf[k], b2f_bits(wfcc[(size_t)k * U_ + u]), acc);
  for (int k = 0; k < U_; ++k) acc = fmaf(hb[k], b2f_bits(wfcc[(size_t)(U_ + k) * U_ + u]), acc);
  float v = fmaxf(acc, 0.f);
  size_t oi = (size_t)B_ * T_ * 600 + (size_t)b * U_ + u;
  if (obf) ((unsigned short*)outraw)[oi] = f2b(v);
  else     ((float*)outraw)[oi] = v;
}

extern "C" void kernel_launch(void* const* d_in, const int* in_sizes, int n_in,
                              void* d_out, int out_size, void* d_ws, size_t ws_size,
                              hipStream_t stream) {
  const void* x    = d_in[0];
  const void* mask = d_in[1];
  const void* kf   = d_in[2];
  const void* rkf  = d_in[3];
  const void* bfw  = d_in[4];
  const void* kb   = d_in[5];
  const void* rkb  = d_in[6];
  const void* bbw  = d_in[7];
  const void* wfc  = d_in[8];
  const void* bfc  = d_in[9];

  char* ws = (char*)d_ws;
  size_t off = 0;
  auto alloc = [&](size_t bytes) { void* p = ws + off; off += (bytes + 255) & ~(size_t)255; return p; };
  int* flags            = (int*)alloc(256);
  int* lens             = (int*)alloc(256);
  unsigned short* xpad  = (unsigned short*)alloc((size_t)65536 * KP * 2);
  unsigned short* kpad  = (unsigned short*)alloc((size_t)2 * KP * NP * 2);
  unsigned short* rkc   = (unsigned short*)alloc((size_t)2 * D_ * NU * 2);
  unsigned short* bpack = (unsigned short*)alloc((size_t)2 * FRAGS_PER_DIR * 512 * 2);
  float* biasc          = (float*)alloc((size_t)2 * 2 * NU * 4);
  unsigned short* wfcc  = (unsigned short*)alloc((size_t)2 * U_ * U_ * 2);
  float* bfcc           = (float*)alloc((size_t)U_ * 4);
  float* hfin           = (float*)alloc((size_t)2 * B_ * 304 * 4);
  void* xp = (void*)(ws + off);
  size_t need_f32 = off + (size_t)2 * 65536 * XPW * 4;
  bool xpf32 = ws_size >= need_f32;

  k_detect<<<dim3(1), dim3(64), 0, stream>>>((const unsigned int*)x, (const unsigned char*)mask, flags);
  k_lengths<<<dim3(B_), dim3(256), 0, stream>>>((const unsigned char*)mask, flags, lens);
  k_xpad<<<dim3(65536 * 40 / 256), dim3(256), 0, stream>>>(x, flags, xpad);
  k_wpad<<<dim3((2 * KP * NP + 255) / 256), dim3(256), 0, stream>>>(kf, kb, flags, kpad);
  k_prep<<<dim3((2 * D_ * NU + 255) / 256), dim3(256), 0, stream>>>(rkf, rkb, bfw, bbw, wfc, bfc,
                                                                    flags, rkc, biasc, wfcc, bfcc);
  k_bpack<<<dim3((2 * FRAGS_PER_DIR * 512 + 255) / 256), dim3(256), 0, stream>>>(rkc, bpack);
  if (xpf32) {
    k_gemm<true><<<dim3(1024, 15, 2), dim3(256), 0, stream>>>(xpad, kpad, biasc, xp);
    k_scan<true><<<dim3(NWGM, 2), dim3(512), 0, stream>>>(bpack, biasc, xp, lens, flags, hfin, d_out);
  } else {
    k_gemm<false><<<dim3(1024, 15, 2), dim3(256), 0, stream>>>(xpad, kpad, biasc, xp);
    k_scan<false><<<dim3(NWGM, 2), dim3(512), 0, stream>>>(bpack, biasc, xp, lens, flags, hfin, d_out);
  }
  k_state<<<dim3(B_), dim3(320), 0, stream>>>(hfin, wfcc, bfcc, flags, d_out);
}